// Round 4
// baseline (249.411 us; speedup 1.0000x reference)
//
#include <hip/hip_runtime.h>
#include <hip/hip_cooperative_groups.h>

// Depth-4 path signature, D=6. SINGLE cooperative kernel: per-wave Chen
// chunk recursion + 3-level combine tree separated by grid.sync().
//
// R9: timing model over R0-R8: dur ~= fill(42-45) + kernel-sum + ~28 fixed;
// R8 kernel-sum ~24-26us of which ~9 is launch ramps/gaps of 4 dispatches +
// latency-bound small combine dispatches. Fix: ONE hipLaunchCooperativeKernel
// (guide-blessed for this harness), grid=256 blocks x 256 thr (1 block/CU,
// co-residency trivial), __launch_bounds__(256,1) = R0's exact VGPR regime
// where the combine ping-pong provably stays in registers (R6/R7 failed at
// 64-128 VGPR caps; this keeps the full budget).
//   phase 1: 1024 chunk-waves (4/block), chunk_len=98, increments in LDS,
//            x2-unrolled zero-padded steps (R8-proven v_pk_fma_f32 form).
//   sync -> 64 blocks fold g=16 -> sync -> 8 blocks fold g=8 -> sync ->
//   block 0 folds 8 -> reference-layout out. Idle waves write zero states
//   (= Chen identity, tail-only, so no clamping anywhere).
//
// State layout (floats), padded stride 1600 (16B-aligned):
//   L4 [0,1296)  L3 [1296,1512)  L2 [1512,1548)  L1 [1548,1554)
// Final output uses reference layout: L1[0,6) L2[6,42) L3[42,258) L4[258,1554).
#define SIGSZ 1554
#define PSTRIDE 1600
#define OFF4 0
#define OFF3 1296
#define OFF2 1512
#define OFF1 1548
#define VROWS 104    // per-wave LDS increment rows; chunk_len <= VROWS-3
#define NSLOTS 1024  // chunk-wave slots = 256 blocks x 4 waves

namespace cg = cooperative_groups;

typedef float v2f __attribute__((ext_vector_type(2)));

__device__ __forceinline__ v2f vfma2(v2f a, v2f b, v2f c) {
  return __builtin_elementwise_fma(a, b, c);
}
__device__ __forceinline__ v2f splat2(float s) {
  v2f r; r.x = s; r.y = s; return r;
}

__device__ __forceinline__ float sel6(int idx, float a0, float a1, float a2,
                                      float a3, float a4, float a5) {
  float r = a0;
  r = (idx == 1) ? a1 : r;
  r = (idx == 2) ? a2 : r;
  r = (idx == 3) ? a3 : r;
  r = (idx == 4) ? a4 : r;
  r = (idx == 5) ? a5 : r;
  return r;
}

// ---------------------------------------------------------------------------
// Chunk phase (per 64-lane wave; lane p<36 owns (i,j)=(p/6,p%6)):
//   S4[ijkl] += G*v_l,  G   = (vi*vj/24 + S1[i]*vj/6 + S2[ij]/2)*vk + S3[ijk]
//   S3[ijk]  += G2*vk,  G2  =  vi*vj/6  + S1[i]*vj/2 + S2[ij]
//   S2[ij]   += (vi/2 + S1[i])*vj ;  S1[i] += vi      (old values on RHS)
// LDS stores increments v_r = x[r+1]-x[r]; rows [steps, steps+3) zeroed so
// the x2-unrolled loop needs no clamps (v=0 is an identity step).
// Level-3/4 state held as float2 pairs -> v_pk_fma_f32 (R8-proven).
// ---------------------------------------------------------------------------
#define DECL4ROW(k) v2f s4_##k##_0 = {0.f, 0.f}, s4_##k##_1 = {0.f, 0.f}, \
                        s4_##k##_2 = {0.f, 0.f};

#define LOADROW(S, row) { \
  const v2f* q_ = (const v2f*)(vsw + (row) * 6); \
  S##p0 = q_[0]; S##p1 = q_[1]; S##p2 = q_[2]; \
  S##vi = vsw[(row) * 6 + i]; S##vj = vsw[(row) * 6 + j]; \
}

#define UPD4K(S, k, gk) { \
  const v2f gk2 = splat2(gk); \
  s4_##k##_0 = vfma2(gk2, S##p0, s4_##k##_0); \
  s4_##k##_1 = vfma2(gk2, S##p1, s4_##k##_1); \
  s4_##k##_2 = vfma2(gk2, S##p2, s4_##k##_2); \
}

#define STEP(S) { \
  const float aa = S##vi * S##vj; \
  const float sv = s1i * S##vj; \
  const float G2 = fmaf(aa, 1.f / 6.f, fmaf(sv, 0.5f, s2)); \
  const float in4 = fmaf(aa, 1.f / 24.f, fmaf(sv, 1.f / 6.f, s2 * 0.5f)); \
  const v2f in42 = splat2(in4), G22 = splat2(G2); \
  const v2f Gp0 = vfma2(in42, S##p0, s3p0); \
  const v2f Gp1 = vfma2(in42, S##p1, s3p1); \
  const v2f Gp2 = vfma2(in42, S##p2, s3p2); \
  s3p0 = vfma2(G22, S##p0, s3p0); \
  s3p1 = vfma2(G22, S##p1, s3p1); \
  s3p2 = vfma2(G22, S##p2, s3p2); \
  UPD4K(S, 0, Gp0.x) UPD4K(S, 1, Gp0.y) UPD4K(S, 2, Gp1.x) \
  UPD4K(S, 3, Gp1.y) UPD4K(S, 4, Gp2.x) UPD4K(S, 5, Gp2.y) \
  s2 = fmaf(fmaf(S##vi, 0.5f, s1i), S##vj, s2); \
  s1i += S##vi; \
}

// ---------------------------------------------------------------------------
// Combine fold (R0-proven structure): product of states [start,end) from
// `in`, left-to-right. 256 lanes; lane t<216 owns (i,j,k), B-slices loaded
// global->named regs, ping-pong prefetched 2 products ahead.
//   C4[ijk,l] = A4 + B4[ijk,l] + A1[i]B3[jk,l] + A2[ij]B2[k,l] + A3[ijk]B1[l]
//   C3[ijk]   = A3 + B3[ijk] + A1[i]B2[jk] + A2[ij]B1[k]
//   C2[ij]    = A2 + B2[ij] + A1[i]B1[j] ;  C1 = A1 + B1   (old A on RHS)
// ---------------------------------------------------------------------------
#define DECLSET(S)                                                  \
  float S##b4_0, S##b4_1, S##b4_2, S##b4_3, S##b4_4, S##b4_5;       \
  float S##b3r_0, S##b3r_1, S##b3r_2, S##b3r_3, S##b3r_4, S##b3r_5; \
  float S##b2r_0, S##b2r_1, S##b2r_2, S##b2r_3, S##b2r_4, S##b2r_5; \
  float S##b1_0, S##b1_1, S##b1_2, S##b1_3, S##b1_4, S##b1_5;       \
  float S##b2ij, S##b2jk, S##b3ijk, S##b1k, S##b1j;

#define LOADSET(S, bp) {                                            \
  const float2* q4 = (const float2*)((bp) + oB4);                   \
  float2 u0 = q4[0], u1 = q4[1], u2 = q4[2];                        \
  S##b4_0 = u0.x; S##b4_1 = u0.y; S##b4_2 = u1.x;                   \
  S##b4_3 = u1.y; S##b4_4 = u2.x; S##b4_5 = u2.y;                   \
  const float2* q3 = (const float2*)((bp) + oB3r);                  \
  float2 w0 = q3[0], w1 = q3[1], w2 = q3[2];                        \
  S##b3r_0 = w0.x; S##b3r_1 = w0.y; S##b3r_2 = w1.x;                \
  S##b3r_3 = w1.y; S##b3r_4 = w2.x; S##b3r_5 = w2.y;                \
  const float2* q2 = (const float2*)((bp) + oB2r);                  \
  float2 y0 = q2[0], y1 = q2[1], y2 = q2[2];                        \
  S##b2r_0 = y0.x; S##b2r_1 = y0.y; S##b2r_2 = y1.x;                \
  S##b2r_3 = y1.y; S##b2r_4 = y2.x; S##b2r_5 = y2.y;                \
  const float2* q1 = (const float2*)((bp) + OFF1);                  \
  float2 z0 = q1[0], z1 = q1[1], z2 = q1[2];                        \
  S##b1_0 = z0.x; S##b1_1 = z0.y; S##b1_2 = z1.x;                   \
  S##b1_3 = z1.y; S##b1_4 = z2.x; S##b1_5 = z2.y;                   \
  S##b2ij = (bp)[oB2ij]; S##b2jk = (bp)[oB2jk];                     \
  S##b3ijk = (bp)[oB3ijk];                                          \
  S##b1k = (bp)[oB1k]; S##b1j = (bp)[oB1j];                         \
}

#define PROD(S) {                                                   \
  const float a1i = sel6(i_, a1_0, a1_1, a1_2, a1_3, a1_4, a1_5);   \
  a4_0 = fmaf(a3, S##b1_0, fmaf(a2, S##b2r_0,                       \
         fmaf(a1i, S##b3r_0, a4_0 + S##b4_0)));                     \
  a4_1 = fmaf(a3, S##b1_1, fmaf(a2, S##b2r_1,                       \
         fmaf(a1i, S##b3r_1, a4_1 + S##b4_1)));                     \
  a4_2 = fmaf(a3, S##b1_2, fmaf(a2, S##b2r_2,                       \
         fmaf(a1i, S##b3r_2, a4_2 + S##b4_2)));                     \
  a4_3 = fmaf(a3, S##b1_3, fmaf(a2, S##b2r_3,                       \
         fmaf(a1i, S##b3r_3, a4_3 + S##b4_3)));                     \
  a4_4 = fmaf(a3, S##b1_4, fmaf(a2, S##b2r_4,                       \
         fmaf(a1i, S##b3r_4, a4_4 + S##b4_4)));                     \
  a4_5 = fmaf(a3, S##b1_5, fmaf(a2, S##b2r_5,                       \
         fmaf(a1i, S##b3r_5, a4_5 + S##b4_5)));                     \
  a3 = fmaf(a2, S##b1k, fmaf(a1i, S##b2jk, a3 + S##b3ijk));         \
  a2 = fmaf(a1i, S##b1j, a2 + S##b2ij);                             \
  a1_0 += S##b1_0; a1_1 += S##b1_1; a1_2 += S##b1_2;                \
  a1_3 += S##b1_3; a1_4 += S##b1_4; a1_5 += S##b1_5;                \
}

__device__ __forceinline__ void combine_fold(const float* __restrict__ in,
                                             float* __restrict__ outp,
                                             int start, int end, int p,
                                             int final_out) {
  const int tc = (p < 216) ? p : 215;
  const bool act = (p < 216);
  const int k_ = tc % 6;
  const int ij = tc / 6;
  const int j_ = ij % 6;
  const int i_ = ij / 6;

  const int oB4 = OFF4 + tc * 6;
  const int oB3r = OFF3 + (j_ * 6 + k_) * 6;
  const int oB2r = OFF2 + k_ * 6;
  const int oB2ij = OFF2 + ij;
  const int oB2jk = OFF2 + j_ * 6 + k_;
  const int oB3ijk = OFF3 + tc;
  const int oB1k = OFF1 + k_;
  const int oB1j = OFF1 + j_;

  // ---- init A from state `start` ----
  const float* sp0 = in + (size_t)start * PSTRIDE;
  float a4_0, a4_1, a4_2, a4_3, a4_4, a4_5;
  {
    const float2* q4 = (const float2*)(sp0 + oB4);
    float2 u0 = q4[0], u1 = q4[1], u2 = q4[2];
    a4_0 = u0.x; a4_1 = u0.y; a4_2 = u1.x;
    a4_3 = u1.y; a4_4 = u2.x; a4_5 = u2.y;
  }
  float a3 = sp0[oB3ijk];
  float a2 = sp0[oB2ij];
  float a1_0, a1_1, a1_2, a1_3, a1_4, a1_5;
  {
    const float2* q1 = (const float2*)(sp0 + OFF1);
    float2 z0 = q1[0], z1 = q1[1], z2 = q1[2];
    a1_0 = z0.x; a1_1 = z0.y; a1_2 = z1.x;
    a1_3 = z1.y; a1_4 = z2.x; a1_5 = z2.y;
  }

  DECLSET(A)
  DECLSET(B)

  int s = start + 1;
  {
    const int sa = (s < end) ? s : (end - 1);
    LOADSET(A, in + (size_t)sa * PSTRIDE)
    const int sb = (s + 1 < end) ? (s + 1) : (end - 1);
    LOADSET(B, in + (size_t)sb * PSTRIDE)
  }
  while (s + 1 < end) {
    PROD(A)
    {
      const int sn = (s + 2 < end) ? (s + 2) : (end - 1);
      LOADSET(A, in + (size_t)sn * PSTRIDE)
    }
    PROD(B)
    {
      const int sn = (s + 3 < end) ? (s + 3) : (end - 1);
      LOADSET(B, in + (size_t)sn * PSTRIDE)
    }
    s += 2;
  }
  if (s < end) { PROD(A) }

  const float a1p = sel6(p, a1_0, a1_1, a1_2, a1_3, a1_4, a1_5);
  if (final_out) {
    float* o = outp;  // reference layout: L1 0, L2 6, L3 42, L4 258
    if (act) {
      float2* o2 = (float2*)(o + 258 + tc * 6);
      float2 w;
      w.x = a4_0; w.y = a4_1; o2[0] = w;
      w.x = a4_2; w.y = a4_3; o2[1] = w;
      w.x = a4_4; w.y = a4_5; o2[2] = w;
      o[42 + tc] = a3;
      if (k_ == 0) o[6 + ij] = a2;
    }
    if (p < 6) o[p] = a1p;
  } else {
    float* st = outp;
    if (act) {
      float2* o2 = (float2*)(st + oB4);
      float2 w;
      w.x = a4_0; w.y = a4_1; o2[0] = w;
      w.x = a4_2; w.y = a4_3; o2[1] = w;
      w.x = a4_4; w.y = a4_5; o2[2] = w;
      st[oB3ijk] = a3;
      if (k_ == 0) st[oB2ij] = a2;
    }
    if (p < 6) st[OFF1 + p] = a1p;
  }
}

// ---------------------------------------------------------------------------
// The single cooperative kernel. grid = 256 blocks x 256 threads (1/CU).
// ---------------------------------------------------------------------------
__global__ __launch_bounds__(256, 1) void sig_all(
    const float* __restrict__ x, float* __restrict__ ws0,
    float* __restrict__ ws1, float* __restrict__ ws2,
    float* __restrict__ out, int n_inc, int chunk_len) {
  cg::grid_group grid = cg::this_grid();
  __shared__ alignas(16) float vs[4 * VROWS * 6];

  // ================= phase 1: per-wave chunk recursion =================
  {
    const int w = threadIdx.x >> 6;          // wave in block (0..3)
    const int lane = threadIdx.x & 63;
    const int c = blockIdx.x * 4 + w;        // chunk-wave slot (0..1023)
    float* vsw = vs + w * (VROWS * 6);

    const int t0 = c * chunk_len;
    int t1 = t0 + chunk_len; if (t1 > n_inc) t1 = n_inc;
    const int steps = (t1 > t0) ? (t1 - t0) : 0;
    const int pc = (lane < 36) ? lane : 35;
    const int i = pc / 6, j = pc % 6;
    const bool act = (lane < 36);

    // stage increments v_r = x[t0+r+1]-x[t0+r]; zero-pad 3 rows (identity)
    const int nv = steps * 6;
    const float* xb = x + (size_t)t0 * 6;
    for (int idx = lane; idx < nv; idx += 64) vsw[idx] = xb[idx + 6] - xb[idx];
    for (int idx = nv + lane; idx < nv + 18; idx += 64) vsw[idx] = 0.f;
    __syncthreads();

    DECL4ROW(0) DECL4ROW(1) DECL4ROW(2) DECL4ROW(3) DECL4ROW(4) DECL4ROW(5)
    v2f s3p0 = {0.f, 0.f}, s3p1 = {0.f, 0.f}, s3p2 = {0.f, 0.f};
    float s1i = 0.f, s2 = 0.f;

    v2f Ap0, Ap1, Ap2; float Avi, Avj;
    v2f Bp0, Bp1, Bp2; float Bvi, Bvj;
    LOADROW(A, 0)
    LOADROW(B, 1)
    const int steps_up = (steps + 1) & ~1;
    for (int r = 0; r < steps_up; r += 2) {
      STEP(A)
      LOADROW(A, r + 2)
      STEP(B)
      LOADROW(B, r + 3)
    }

    // store state c (idle waves store zeros = Chen identity; tail-only)
    float* st = ws0 + (size_t)c * PSTRIDE;
    if (act) {
      float4* o4 = (float4*)(st + OFF4 + pc * 36);
      float4 wq;
      wq.x = s4_0_0.x; wq.y = s4_0_0.y; wq.z = s4_0_1.x; wq.w = s4_0_1.y; o4[0] = wq;
      wq.x = s4_0_2.x; wq.y = s4_0_2.y; wq.z = s4_1_0.x; wq.w = s4_1_0.y; o4[1] = wq;
      wq.x = s4_1_1.x; wq.y = s4_1_1.y; wq.z = s4_1_2.x; wq.w = s4_1_2.y; o4[2] = wq;
      wq.x = s4_2_0.x; wq.y = s4_2_0.y; wq.z = s4_2_1.x; wq.w = s4_2_1.y; o4[3] = wq;
      wq.x = s4_2_2.x; wq.y = s4_2_2.y; wq.z = s4_3_0.x; wq.w = s4_3_0.y; o4[4] = wq;
      wq.x = s4_3_1.x; wq.y = s4_3_1.y; wq.z = s4_3_2.x; wq.w = s4_3_2.y; o4[5] = wq;
      wq.x = s4_4_0.x; wq.y = s4_4_0.y; wq.z = s4_4_1.x; wq.w = s4_4_1.y; o4[6] = wq;
      wq.x = s4_4_2.x; wq.y = s4_4_2.y; wq.z = s4_5_0.x; wq.w = s4_5_0.y; o4[7] = wq;
      wq.x = s4_5_1.x; wq.y = s4_5_1.y; wq.z = s4_5_2.x; wq.w = s4_5_2.y; o4[8] = wq;
      st[OFF3 + pc * 6 + 0] = s3p0.x;
      st[OFF3 + pc * 6 + 1] = s3p0.y;
      st[OFF3 + pc * 6 + 2] = s3p1.x;
      st[OFF3 + pc * 6 + 3] = s3p1.y;
      st[OFF3 + pc * 6 + 4] = s3p2.x;
      st[OFF3 + pc * 6 + 5] = s3p2.y;
      st[OFF2 + pc] = s2;
      if (j == 0) st[OFF1 + i] = s1i;
    }
  }

  __threadfence();
  grid.sync();

  // ============ phase 2: 1024 -> 64 (64 blocks fold g=16) ============
  if (blockIdx.x < 64) {
    combine_fold(ws0, ws1 + (size_t)blockIdx.x * PSTRIDE,
                 blockIdx.x * 16, blockIdx.x * 16 + 16, threadIdx.x, 0);
  }
  __threadfence();
  grid.sync();

  // ============ phase 3: 64 -> 8 (8 blocks fold g=8) ============
  if (blockIdx.x < 8) {
    combine_fold(ws1, ws2 + (size_t)blockIdx.x * PSTRIDE,
                 blockIdx.x * 8, blockIdx.x * 8 + 8, threadIdx.x, 0);
  }
  __threadfence();
  grid.sync();

  // ============ phase 4: 8 -> 1, final reference-layout store ============
  if (blockIdx.x == 0) {
    combine_fold(ws2, out, 0, 8, threadIdx.x, 1);
  }
}

extern "C" void kernel_launch(void* const* d_in, const int* in_sizes, int n_in,
                              void* d_out, int out_size, void* d_ws, size_t ws_size,
                              hipStream_t stream) {
  const float* x = (const float*)d_in[0];
  const int Lrows = in_sizes[0] / 6;
  const int n_inc = Lrows - 1;

  int chunk_len = (n_inc + NSLOTS - 1) / NSLOTS;   // 98 for L=100000
  if (chunk_len < 1) chunk_len = 1;
  // chunk_len <= VROWS-3 holds for all n_inc <= 1024*101 (true here)

  float* ws0 = (float*)d_ws;                        // 1024 chunk states
  float* ws1 = ws0 + (size_t)NSLOTS * PSTRIDE;      // 64 partials
  float* ws2 = ws1 + (size_t)64 * PSTRIDE;          // 8 partials
  float* o = (float*)d_out;

  void* args[] = {(void*)&x, (void*)&ws0, (void*)&ws1, (void*)&ws2,
                  (void*)&o, (void*)&n_inc, (void*)&chunk_len};
  hipLaunchCooperativeKernel((const void*)sig_all, dim3(256), dim3(256),
                             args, 0, stream);
}

// Round 5
// 86.227 us; speedup vs baseline: 2.8925x; 2.8925x over previous
//
#include <hip/hip_runtime.h>

// Depth-4 path signature, D=6. Chunked Chen recursion + 3-level combine tree.
//
// R10: revert to the PROVEN 4-dispatch structure (R0=94.5us, R8=98.4 with
// slower fills). R6/R7/R9 proved 3x that any merged mega-kernel makes the
// allocator target high occupancy (VGPR 64-68) and spill the ~100-float
// per-lane state -> 2-4x regression. Do NOT merge kernels again.
// This round's lever: combine links are cross-XCD load-latency chains
// (~500-900cyc/LOADSET, ping-pong depth 2 -> ~250+cyc/link). Prefetch depth
// 2 -> 4 (sets A-D, ~170 VGPR, inside launch_bounds(256,1) budget where this
// idiom provably stays in registers). P=2048 (R0 config, halves level-1
// traffic vs R8). Chunk = R8's verbatim v2f (v_pk_fma_f32) version.
//
// State layout (floats), padded stride 1600 (16B-aligned):
//   L4 [0,1296)  L3 [1296,1512)  L2 [1512,1548)  L1 [1548,1554)
// Final output uses reference layout: L1[0,6) L2[6,42) L3[42,258) L4[258,1554).
#define SIGSZ 1554
#define PSTRIDE 1600
#define OFF4 0
#define OFF3 1296
#define OFF2 1512
#define OFF1 1548
#define VROWS 64     // LDS increment-row capacity; chunk_len <= VROWS-3
#define PMAX 2048

typedef float v2f __attribute__((ext_vector_type(2)));

__device__ __forceinline__ v2f vfma2(v2f a, v2f b, v2f c) {
  return __builtin_elementwise_fma(a, b, c);
}
__device__ __forceinline__ v2f splat2(float s) {
  v2f r; r.x = s; r.y = s; return r;
}

__device__ __forceinline__ float sel6(int idx, float a0, float a1, float a2,
                                      float a3, float a4, float a5) {
  float r = a0;
  r = (idx == 1) ? a1 : r;
  r = (idx == 2) ? a2 : r;
  r = (idx == 3) ? a3 : r;
  r = (idx == 4) ? a4 : r;
  r = (idx == 5) ? a5 : r;
  return r;
}

// ---------------------------------------------------------------------------
// Phase 1: one 64-thread block per chunk; lane p<36 owns (i,j)=(p/6,p%6).
//   S4[ijkl] += G*v_l,  G   = (vi*vj/24 + S1[i]*vj/6 + S2[ij]/2)*vk + S3[ijk]
//   S3[ijk]  += G2*vk,  G2  =  vi*vj/6  + S1[i]*vj/2 + S2[ij]
//   S2[ij]   += (vi/2 + S1[i])*vj ;  S1[i] += vi      (old values on RHS)
// LDS stores increments v_r = x[r+1]-x[r]; rows [steps, steps+3) zeroed so
// the x2-unrolled loop needs no clamps (v=0 is an identity step).
// Level-3/4 state held as float2 pairs -> v_pk_fma_f32 (R8-proven).
// ---------------------------------------------------------------------------
#define DECL4ROW(k) v2f s4_##k##_0 = {0.f, 0.f}, s4_##k##_1 = {0.f, 0.f}, \
                        s4_##k##_2 = {0.f, 0.f};

#define LOADROW(S, row) { \
  const v2f* q_ = (const v2f*)(vs + (row) * 6); \
  S##p0 = q_[0]; S##p1 = q_[1]; S##p2 = q_[2]; \
  S##vi = vs[(row) * 6 + i]; S##vj = vs[(row) * 6 + j]; \
}

#define UPD4K(S, k, gk) { \
  const v2f gk2 = splat2(gk); \
  s4_##k##_0 = vfma2(gk2, S##p0, s4_##k##_0); \
  s4_##k##_1 = vfma2(gk2, S##p1, s4_##k##_1); \
  s4_##k##_2 = vfma2(gk2, S##p2, s4_##k##_2); \
}

#define STEP(S) { \
  const float aa = S##vi * S##vj; \
  const float sv = s1i * S##vj; \
  const float G2 = fmaf(aa, 1.f / 6.f, fmaf(sv, 0.5f, s2)); \
  const float in4 = fmaf(aa, 1.f / 24.f, fmaf(sv, 1.f / 6.f, s2 * 0.5f)); \
  const v2f in42 = splat2(in4), G22 = splat2(G2); \
  const v2f Gp0 = vfma2(in42, S##p0, s3p0); \
  const v2f Gp1 = vfma2(in42, S##p1, s3p1); \
  const v2f Gp2 = vfma2(in42, S##p2, s3p2); \
  s3p0 = vfma2(G22, S##p0, s3p0); \
  s3p1 = vfma2(G22, S##p1, s3p1); \
  s3p2 = vfma2(G22, S##p2, s3p2); \
  UPD4K(S, 0, Gp0.x) UPD4K(S, 1, Gp0.y) UPD4K(S, 2, Gp1.x) \
  UPD4K(S, 3, Gp1.y) UPD4K(S, 4, Gp2.x) UPD4K(S, 5, Gp2.y) \
  s2 = fmaf(fmaf(S##vi, 0.5f, s1i), S##vj, s2); \
  s1i += S##vi; \
}

__global__ __launch_bounds__(64, 4) void sig_chunk(const float* __restrict__ x,
                                                   float* __restrict__ out,
                                                   int n_inc, int chunk_len) {
  __shared__ alignas(16) float vs[VROWS * 6];
  const int c = blockIdx.x;
  const int p = threadIdx.x;
  const int t0 = c * chunk_len;
  int t1 = t0 + chunk_len; if (t1 > n_inc) t1 = n_inc;
  const int steps = (t1 > t0) ? (t1 - t0) : 0;
  const int pc = (p < 36) ? p : 35;
  const int i = pc / 6, j = pc % 6;
  const bool act = (p < 36);

  // ---- stage increments v_r = x[t0+r+1] - x[t0+r]; zero-pad 3 rows ----
  const int nv = steps * 6;
  const float* xb = x + (size_t)t0 * 6;
  for (int idx = p; idx < nv; idx += 64) vs[idx] = xb[idx + 6] - xb[idx];
  for (int idx = nv + p; idx < nv + 18; idx += 64) vs[idx] = 0.f;
  __syncthreads();

  DECL4ROW(0) DECL4ROW(1) DECL4ROW(2) DECL4ROW(3) DECL4ROW(4) DECL4ROW(5)
  v2f s3p0 = {0.f, 0.f}, s3p1 = {0.f, 0.f}, s3p2 = {0.f, 0.f};
  float s1i = 0.f, s2 = 0.f;

  v2f Ap0, Ap1, Ap2; float Avi, Avj;
  v2f Bp0, Bp1, Bp2; float Bvi, Bvj;
  LOADROW(A, 0)
  LOADROW(B, 1)
  const int steps_up = (steps + 1) & ~1;
  for (int r = 0; r < steps_up; r += 2) {
    STEP(A)
    LOADROW(A, r + 2)
    STEP(B)
    LOADROW(B, r + 3)
  }

  float* st = out + (size_t)c * PSTRIDE;
  if (act) {
    float4* o4 = (float4*)(st + OFF4 + pc * 36);
    float4 w;
    w.x = s4_0_0.x; w.y = s4_0_0.y; w.z = s4_0_1.x; w.w = s4_0_1.y; o4[0] = w;
    w.x = s4_0_2.x; w.y = s4_0_2.y; w.z = s4_1_0.x; w.w = s4_1_0.y; o4[1] = w;
    w.x = s4_1_1.x; w.y = s4_1_1.y; w.z = s4_1_2.x; w.w = s4_1_2.y; o4[2] = w;
    w.x = s4_2_0.x; w.y = s4_2_0.y; w.z = s4_2_1.x; w.w = s4_2_1.y; o4[3] = w;
    w.x = s4_2_2.x; w.y = s4_2_2.y; w.z = s4_3_0.x; w.w = s4_3_0.y; o4[4] = w;
    w.x = s4_3_1.x; w.y = s4_3_1.y; w.z = s4_3_2.x; w.w = s4_3_2.y; o4[5] = w;
    w.x = s4_4_0.x; w.y = s4_4_0.y; w.z = s4_4_1.x; w.w = s4_4_1.y; o4[6] = w;
    w.x = s4_4_2.x; w.y = s4_4_2.y; w.z = s4_5_0.x; w.w = s4_5_0.y; o4[7] = w;
    w.x = s4_5_1.x; w.y = s4_5_1.y; w.z = s4_5_2.x; w.w = s4_5_2.y; o4[8] = w;
    st[OFF3 + pc * 6 + 0] = s3p0.x;
    st[OFF3 + pc * 6 + 1] = s3p0.y;
    st[OFF3 + pc * 6 + 2] = s3p1.x;
    st[OFF3 + pc * 6 + 3] = s3p1.y;
    st[OFF3 + pc * 6 + 4] = s3p2.x;
    st[OFF3 + pc * 6 + 5] = s3p2.y;
    st[OFF2 + pc] = s2;
    if (j == 0) st[OFF1 + i] = s1i;
  }
}

// ---------------------------------------------------------------------------
// Phase 2 (R0-proven shape, prefetch depth 4): combine `group` consecutive
// states left-to-right. 256-thread blocks; lane t<216 owns (i,j,k), keeping
// C4[ijk,:] (6), C3[ijk], and REDUNDANT copies of C2[ij], C1[:] in regs.
// B-slices loaded global->named regs, prefetched FOUR products ahead
// (cross-XCD link latency ~500-900cyc; depth 4 -> ~latency/4 per link).
//   C4[ijk,l] = A4 + B4[ijk,l] + A1[i]B3[jk,l] + A2[ij]B2[k,l] + A3[ijk]B1[l]
//   C3[ijk]   = A3 + B3[ijk] + A1[i]B2[jk] + A2[ij]B1[k]
//   C2[ij]    = A2 + B2[ij] + A1[i]B1[j] ;  C1 = A1 + B1   (old A on RHS)
// ---------------------------------------------------------------------------

// 31 named scalars per prefetch set
#define DECLSET(S)                                                  \
  float S##b4_0, S##b4_1, S##b4_2, S##b4_3, S##b4_4, S##b4_5;       \
  float S##b3r_0, S##b3r_1, S##b3r_2, S##b3r_3, S##b3r_4, S##b3r_5; \
  float S##b2r_0, S##b2r_1, S##b2r_2, S##b2r_3, S##b2r_4, S##b2r_5; \
  float S##b1_0, S##b1_1, S##b1_2, S##b1_3, S##b1_4, S##b1_5;       \
  float S##b2ij, S##b2jk, S##b3ijk, S##b1k, S##b1j;

#define LOADSET(S, bp) {                                            \
  const float2* q4 = (const float2*)((bp) + oB4);                   \
  float2 u0 = q4[0], u1 = q4[1], u2 = q4[2];                        \
  S##b4_0 = u0.x; S##b4_1 = u0.y; S##b4_2 = u1.x;                   \
  S##b4_3 = u1.y; S##b4_4 = u2.x; S##b4_5 = u2.y;                   \
  const float2* q3 = (const float2*)((bp) + oB3r);                  \
  float2 w0 = q3[0], w1 = q3[1], w2 = q3[2];                        \
  S##b3r_0 = w0.x; S##b3r_1 = w0.y; S##b3r_2 = w1.x;                \
  S##b3r_3 = w1.y; S##b3r_4 = w2.x; S##b3r_5 = w2.y;                \
  const float2* q2 = (const float2*)((bp) + oB2r);                  \
  float2 y0 = q2[0], y1 = q2[1], y2 = q2[2];                        \
  S##b2r_0 = y0.x; S##b2r_1 = y0.y; S##b2r_2 = y1.x;                \
  S##b2r_3 = y1.y; S##b2r_4 = y2.x; S##b2r_5 = y2.y;                \
  const float2* q1 = (const float2*)((bp) + OFF1);                  \
  float2 z0 = q1[0], z1 = q1[1], z2 = q1[2];                        \
  S##b1_0 = z0.x; S##b1_1 = z0.y; S##b1_2 = z1.x;                   \
  S##b1_3 = z1.y; S##b1_4 = z2.x; S##b1_5 = z2.y;                   \
  S##b2ij = (bp)[oB2ij]; S##b2jk = (bp)[oB2jk];                     \
  S##b3ijk = (bp)[oB3ijk];                                          \
  S##b1k = (bp)[oB1k]; S##b1j = (bp)[oB1j];                         \
}

#define PROD(S) {                                                   \
  const float a1i = sel6(i_, a1_0, a1_1, a1_2, a1_3, a1_4, a1_5);   \
  a4_0 = fmaf(a3, S##b1_0, fmaf(a2, S##b2r_0,                       \
         fmaf(a1i, S##b3r_0, a4_0 + S##b4_0)));                     \
  a4_1 = fmaf(a3, S##b1_1, fmaf(a2, S##b2r_1,                       \
         fmaf(a1i, S##b3r_1, a4_1 + S##b4_1)));                     \
  a4_2 = fmaf(a3, S##b1_2, fmaf(a2, S##b2r_2,                       \
         fmaf(a1i, S##b3r_2, a4_2 + S##b4_2)));                     \
  a4_3 = fmaf(a3, S##b1_3, fmaf(a2, S##b2r_3,                       \
         fmaf(a1i, S##b3r_3, a4_3 + S##b4_3)));                     \
  a4_4 = fmaf(a3, S##b1_4, fmaf(a2, S##b2r_4,                       \
         fmaf(a1i, S##b3r_4, a4_4 + S##b4_4)));                     \
  a4_5 = fmaf(a3, S##b1_5, fmaf(a2, S##b2r_5,                       \
         fmaf(a1i, S##b3r_5, a4_5 + S##b4_5)));                     \
  a3 = fmaf(a2, S##b1k, fmaf(a1i, S##b2jk, a3 + S##b3ijk));         \
  a2 = fmaf(a1i, S##b1j, a2 + S##b2ij);                             \
  a1_0 += S##b1_0; a1_1 += S##b1_1; a1_2 += S##b1_2;                \
  a1_3 += S##b1_3; a1_4 += S##b1_4; a1_5 += S##b1_5;                \
}

__global__ __launch_bounds__(256, 1) void sig_combine(const float* __restrict__ in,
                                                      float* __restrict__ out,
                                                      int n_total, int group,
                                                      int final_out) {
  const int b = blockIdx.x;
  const int p = threadIdx.x;
  const int start = b * group;
  int end = start + group; if (end > n_total) end = n_total;
  const int tc = (p < 216) ? p : 215;
  const bool act = (p < 216);
  const int k_ = tc % 6;
  const int ij = tc / 6;
  const int j_ = ij % 6;
  const int i_ = ij / 6;

  // loop-invariant element offsets
  const int oB4 = OFF4 + tc * 6;
  const int oB3r = OFF3 + (j_ * 6 + k_) * 6;
  const int oB2r = OFF2 + k_ * 6;
  const int oB2ij = OFF2 + ij;
  const int oB2jk = OFF2 + j_ * 6 + k_;
  const int oB3ijk = OFF3 + tc;
  const int oB1k = OFF1 + k_;
  const int oB1j = OFF1 + j_;

  // ---- init A from state `start` ----
  const float* sp0 = in + (size_t)start * PSTRIDE;
  float a4_0, a4_1, a4_2, a4_3, a4_4, a4_5;
  {
    const float2* q4 = (const float2*)(sp0 + oB4);
    float2 u0 = q4[0], u1 = q4[1], u2 = q4[2];
    a4_0 = u0.x; a4_1 = u0.y; a4_2 = u1.x;
    a4_3 = u1.y; a4_4 = u2.x; a4_5 = u2.y;
  }
  float a3 = sp0[oB3ijk];
  float a2 = sp0[oB2ij];
  float a1_0, a1_1, a1_2, a1_3, a1_4, a1_5;
  {
    const float2* q1 = (const float2*)(sp0 + OFF1);
    float2 z0 = q1[0], z1 = q1[1], z2 = q1[2];
    a1_0 = z0.x; a1_1 = z0.y; a1_2 = z1.x;
    a1_3 = z1.y; a1_4 = z2.x; a1_5 = z2.y;
  }

  DECLSET(A)
  DECLSET(B)
  DECLSET(C)
  DECLSET(D)

#define CLAMP_S(t) (((t) < end) ? (t) : (end - 1))
  int s = start + 1;
  {
    LOADSET(A, in + (size_t)CLAMP_S(s) * PSTRIDE)
    LOADSET(B, in + (size_t)CLAMP_S(s + 1) * PSTRIDE)
    LOADSET(C, in + (size_t)CLAMP_S(s + 2) * PSTRIDE)
    LOADSET(D, in + (size_t)CLAMP_S(s + 3) * PSTRIDE)
  }
  while (s + 3 < end) {
    PROD(A)
    LOADSET(A, in + (size_t)CLAMP_S(s + 4) * PSTRIDE)
    PROD(B)
    LOADSET(B, in + (size_t)CLAMP_S(s + 5) * PSTRIDE)
    PROD(C)
    LOADSET(C, in + (size_t)CLAMP_S(s + 6) * PSTRIDE)
    PROD(D)
    LOADSET(D, in + (size_t)CLAMP_S(s + 7) * PSTRIDE)
    s += 4;
  }
  // tail: at most 3 remaining links, held in A,B,C (D would imply s+3<end)
  if (s < end) { PROD(A) }
  if (s + 1 < end) { PROD(B) }
  if (s + 2 < end) { PROD(C) }
#undef CLAMP_S

  const float a1p = sel6(p, a1_0, a1_1, a1_2, a1_3, a1_4, a1_5);
  if (final_out) {
    float* o = out;   // reference layout: L1 0, L2 6, L3 42, L4 258
    if (act) {
      float2* o2 = (float2*)(o + 258 + tc * 6);
      float2 w;
      w.x = a4_0; w.y = a4_1; o2[0] = w;
      w.x = a4_2; w.y = a4_3; o2[1] = w;
      w.x = a4_4; w.y = a4_5; o2[2] = w;
      o[42 + tc] = a3;
      if (k_ == 0) o[6 + ij] = a2;
    }
    if (p < 6) o[p] = a1p;
  } else {
    float* st = out + (size_t)b * PSTRIDE;
    if (act) {
      float2* o2 = (float2*)(st + oB4);
      float2 w;
      w.x = a4_0; w.y = a4_1; o2[0] = w;
      w.x = a4_2; w.y = a4_3; o2[1] = w;
      w.x = a4_4; w.y = a4_5; o2[2] = w;
      st[oB3ijk] = a3;
      if (k_ == 0) st[oB2ij] = a2;
    }
    if (p < 6) st[OFF1 + p] = a1p;
  }
}

extern "C" void kernel_launch(void* const* d_in, const int* in_sizes, int n_in,
                              void* d_out, int out_size, void* d_ws, size_t ws_size,
                              hipStream_t stream) {
  const float* x = (const float*)d_in[0];
  const int Lrows = in_sizes[0] / 6;
  const int n_inc = Lrows - 1;

  int P = PMAX;
  int chunk_len = (n_inc + P - 1) / P;
  if (chunk_len > VROWS - 3) {             // keep LDS increment staging in bounds
    chunk_len = VROWS - 3;
    P = (n_inc + chunk_len - 1) / chunk_len;
  }

  float* ws0 = (float*)d_ws;                               // P chunk states
  float* ws1 = ws0 + (size_t)PMAX * PSTRIDE;               // tree partials

  sig_chunk<<<P, 64, 0, stream>>>(x, ws0, n_inc, chunk_len);

  float* cur = ws0;
  float* other = ws1;
  int n = P;
  while (n > 1) {
    const int g = (n <= 16) ? n : 16;
    const int nb = (n + g - 1) / g;
    const int fin = (nb == 1);
    sig_combine<<<nb, 256, 0, stream>>>(cur, fin ? (float*)d_out : other, n, g, fin);
    float* t = cur; cur = other; other = t;
    n = nb;
  }
}

// Round 6
// 85.897 us; speedup vs baseline: 2.9036x; 1.0038x over previous
//
#include <hip/hip_runtime.h>

// Depth-4 path signature, D=6. Chunked Chen recursion + 3-level combine tree.
//
// R11: R10 (86.2us, best) + ONE lever: pin the register-allocator's occupancy
// target with amdgpu_waves_per_eu. Evidence across R1/R2/R9: the backend's
// occupancy-driven scheduler SINKS the prefetch loads (VGPR 64-68 despite
// launch_bounds budgets) -- launch_bounds' 2nd arg sets only the MIN waves/EU
// (budget), not the scheduler's occupancy target. sig_combine gets (1,1): at
// a fixed 1-wave/EU target, sinking buys nothing, so the depth-4 ping-pong
// (~170 VGPR) stays resident and each link is VALU-bound (~150cyc) instead of
// L2/LLC-latency-bound (~400-600cyc). sig_chunk gets (2,2): budget 256 VGPR
// (needs ~110; default 8-wave target = 64 VGPR would spill s4), and P=2048
// only provides 2 waves/SIMD anyway. All else byte-identical to R10.
// DO NOT merge kernels (R6/R7/R9: 3x proven allocator betrayal).
//
// State layout (floats), padded stride 1600 (16B-aligned):
//   L4 [0,1296)  L3 [1296,1512)  L2 [1512,1548)  L1 [1548,1554)
// Final output uses reference layout: L1[0,6) L2[6,42) L3[42,258) L4[258,1554).
#define SIGSZ 1554
#define PSTRIDE 1600
#define OFF4 0
#define OFF3 1296
#define OFF2 1512
#define OFF1 1548
#define VROWS 64     // LDS increment-row capacity; chunk_len <= VROWS-3
#define PMAX 2048

typedef float v2f __attribute__((ext_vector_type(2)));

__device__ __forceinline__ v2f vfma2(v2f a, v2f b, v2f c) {
  return __builtin_elementwise_fma(a, b, c);
}
__device__ __forceinline__ v2f splat2(float s) {
  v2f r; r.x = s; r.y = s; return r;
}

__device__ __forceinline__ float sel6(int idx, float a0, float a1, float a2,
                                      float a3, float a4, float a5) {
  float r = a0;
  r = (idx == 1) ? a1 : r;
  r = (idx == 2) ? a2 : r;
  r = (idx == 3) ? a3 : r;
  r = (idx == 4) ? a4 : r;
  r = (idx == 5) ? a5 : r;
  return r;
}

// ---------------------------------------------------------------------------
// Phase 1: one 64-thread block per chunk; lane p<36 owns (i,j)=(p/6,p%6).
//   S4[ijkl] += G*v_l,  G   = (vi*vj/24 + S1[i]*vj/6 + S2[ij]/2)*vk + S3[ijk]
//   S3[ijk]  += G2*vk,  G2  =  vi*vj/6  + S1[i]*vj/2 + S2[ij]
//   S2[ij]   += (vi/2 + S1[i])*vj ;  S1[i] += vi      (old values on RHS)
// LDS stores increments v_r = x[r+1]-x[r]; rows [steps, steps+3) zeroed so
// the x2-unrolled loop needs no clamps (v=0 is an identity step).
// Level-3/4 state held as float2 pairs -> v_pk_fma_f32 (R8-proven).
// ---------------------------------------------------------------------------
#define DECL4ROW(k) v2f s4_##k##_0 = {0.f, 0.f}, s4_##k##_1 = {0.f, 0.f}, \
                        s4_##k##_2 = {0.f, 0.f};

#define LOADROW(S, row) { \
  const v2f* q_ = (const v2f*)(vs + (row) * 6); \
  S##p0 = q_[0]; S##p1 = q_[1]; S##p2 = q_[2]; \
  S##vi = vs[(row) * 6 + i]; S##vj = vs[(row) * 6 + j]; \
}

#define UPD4K(S, k, gk) { \
  const v2f gk2 = splat2(gk); \
  s4_##k##_0 = vfma2(gk2, S##p0, s4_##k##_0); \
  s4_##k##_1 = vfma2(gk2, S##p1, s4_##k##_1); \
  s4_##k##_2 = vfma2(gk2, S##p2, s4_##k##_2); \
}

#define STEP(S) { \
  const float aa = S##vi * S##vj; \
  const float sv = s1i * S##vj; \
  const float G2 = fmaf(aa, 1.f / 6.f, fmaf(sv, 0.5f, s2)); \
  const float in4 = fmaf(aa, 1.f / 24.f, fmaf(sv, 1.f / 6.f, s2 * 0.5f)); \
  const v2f in42 = splat2(in4), G22 = splat2(G2); \
  const v2f Gp0 = vfma2(in42, S##p0, s3p0); \
  const v2f Gp1 = vfma2(in42, S##p1, s3p1); \
  const v2f Gp2 = vfma2(in42, S##p2, s3p2); \
  s3p0 = vfma2(G22, S##p0, s3p0); \
  s3p1 = vfma2(G22, S##p1, s3p1); \
  s3p2 = vfma2(G22, S##p2, s3p2); \
  UPD4K(S, 0, Gp0.x) UPD4K(S, 1, Gp0.y) UPD4K(S, 2, Gp1.x) \
  UPD4K(S, 3, Gp1.y) UPD4K(S, 4, Gp2.x) UPD4K(S, 5, Gp2.y) \
  s2 = fmaf(fmaf(S##vi, 0.5f, s1i), S##vj, s2); \
  s1i += S##vi; \
}

__global__ __launch_bounds__(64)
__attribute__((amdgpu_waves_per_eu(2, 2)))
void sig_chunk(const float* __restrict__ x,
               float* __restrict__ out,
               int n_inc, int chunk_len) {
  __shared__ alignas(16) float vs[VROWS * 6];
  const int c = blockIdx.x;
  const int p = threadIdx.x;
  const int t0 = c * chunk_len;
  int t1 = t0 + chunk_len; if (t1 > n_inc) t1 = n_inc;
  const int steps = (t1 > t0) ? (t1 - t0) : 0;
  const int pc = (p < 36) ? p : 35;
  const int i = pc / 6, j = pc % 6;
  const bool act = (p < 36);

  // ---- stage increments v_r = x[t0+r+1] - x[t0+r]; zero-pad 3 rows ----
  const int nv = steps * 6;
  const float* xb = x + (size_t)t0 * 6;
  for (int idx = p; idx < nv; idx += 64) vs[idx] = xb[idx + 6] - xb[idx];
  for (int idx = nv + p; idx < nv + 18; idx += 64) vs[idx] = 0.f;
  __syncthreads();

  DECL4ROW(0) DECL4ROW(1) DECL4ROW(2) DECL4ROW(3) DECL4ROW(4) DECL4ROW(5)
  v2f s3p0 = {0.f, 0.f}, s3p1 = {0.f, 0.f}, s3p2 = {0.f, 0.f};
  float s1i = 0.f, s2 = 0.f;

  v2f Ap0, Ap1, Ap2; float Avi, Avj;
  v2f Bp0, Bp1, Bp2; float Bvi, Bvj;
  LOADROW(A, 0)
  LOADROW(B, 1)
  const int steps_up = (steps + 1) & ~1;
  for (int r = 0; r < steps_up; r += 2) {
    STEP(A)
    LOADROW(A, r + 2)
    STEP(B)
    LOADROW(B, r + 3)
  }

  float* st = out + (size_t)c * PSTRIDE;
  if (act) {
    float4* o4 = (float4*)(st + OFF4 + pc * 36);
    float4 w;
    w.x = s4_0_0.x; w.y = s4_0_0.y; w.z = s4_0_1.x; w.w = s4_0_1.y; o4[0] = w;
    w.x = s4_0_2.x; w.y = s4_0_2.y; w.z = s4_1_0.x; w.w = s4_1_0.y; o4[1] = w;
    w.x = s4_1_1.x; w.y = s4_1_1.y; w.z = s4_1_2.x; w.w = s4_1_2.y; o4[2] = w;
    w.x = s4_2_0.x; w.y = s4_2_0.y; w.z = s4_2_1.x; w.w = s4_2_1.y; o4[3] = w;
    w.x = s4_2_2.x; w.y = s4_2_2.y; w.z = s4_3_0.x; w.w = s4_3_0.y; o4[4] = w;
    w.x = s4_3_1.x; w.y = s4_3_1.y; w.z = s4_3_2.x; w.w = s4_3_2.y; o4[5] = w;
    w.x = s4_4_0.x; w.y = s4_4_0.y; w.z = s4_4_1.x; w.w = s4_4_1.y; o4[6] = w;
    w.x = s4_4_2.x; w.y = s4_4_2.y; w.z = s4_5_0.x; w.w = s4_5_0.y; o4[7] = w;
    w.x = s4_5_1.x; w.y = s4_5_1.y; w.z = s4_5_2.x; w.w = s4_5_2.y; o4[8] = w;
    st[OFF3 + pc * 6 + 0] = s3p0.x;
    st[OFF3 + pc * 6 + 1] = s3p0.y;
    st[OFF3 + pc * 6 + 2] = s3p1.x;
    st[OFF3 + pc * 6 + 3] = s3p1.y;
    st[OFF3 + pc * 6 + 4] = s3p2.x;
    st[OFF3 + pc * 6 + 5] = s3p2.y;
    st[OFF2 + pc] = s2;
    if (j == 0) st[OFF1 + i] = s1i;
  }
}

// ---------------------------------------------------------------------------
// Phase 2 (R10-proven shape, prefetch depth 4 + pinned 1-wave/EU target):
// combine `group` consecutive states left-to-right. 256-thread blocks; lane
// t<216 owns (i,j,k), keeping C4[ijk,:] (6), C3[ijk], and REDUNDANT copies of
// C2[ij], C1[:] in regs. B-slices loaded global->named regs, prefetched FOUR
// products ahead; amdgpu_waves_per_eu(1,1) stops the scheduler from sinking
// the prefetches for occupancy (the R1/R2/R9 failure mode).
//   C4[ijk,l] = A4 + B4[ijk,l] + A1[i]B3[jk,l] + A2[ij]B2[k,l] + A3[ijk]B1[l]
//   C3[ijk]   = A3 + B3[ijk] + A1[i]B2[jk] + A2[ij]B1[k]
//   C2[ij]    = A2 + B2[ij] + A1[i]B1[j] ;  C1 = A1 + B1   (old A on RHS)
// ---------------------------------------------------------------------------

// 31 named scalars per prefetch set
#define DECLSET(S)                                                  \
  float S##b4_0, S##b4_1, S##b4_2, S##b4_3, S##b4_4, S##b4_5;       \
  float S##b3r_0, S##b3r_1, S##b3r_2, S##b3r_3, S##b3r_4, S##b3r_5; \
  float S##b2r_0, S##b2r_1, S##b2r_2, S##b2r_3, S##b2r_4, S##b2r_5; \
  float S##b1_0, S##b1_1, S##b1_2, S##b1_3, S##b1_4, S##b1_5;       \
  float S##b2ij, S##b2jk, S##b3ijk, S##b1k, S##b1j;

#define LOADSET(S, bp) {                                            \
  const float2* q4 = (const float2*)((bp) + oB4);                   \
  float2 u0 = q4[0], u1 = q4[1], u2 = q4[2];                        \
  S##b4_0 = u0.x; S##b4_1 = u0.y; S##b4_2 = u1.x;                   \
  S##b4_3 = u1.y; S##b4_4 = u2.x; S##b4_5 = u2.y;                   \
  const float2* q3 = (const float2*)((bp) + oB3r);                  \
  float2 w0 = q3[0], w1 = q3[1], w2 = q3[2];                        \
  S##b3r_0 = w0.x; S##b3r_1 = w0.y; S##b3r_2 = w1.x;                \
  S##b3r_3 = w1.y; S##b3r_4 = w2.x; S##b3r_5 = w2.y;                \
  const float2* q2 = (const float2*)((bp) + oB2r);                  \
  float2 y0 = q2[0], y1 = q2[1], y2 = q2[2];                        \
  S##b2r_0 = y0.x; S##b2r_1 = y0.y; S##b2r_2 = y1.x;                \
  S##b2r_3 = y1.y; S##b2r_4 = y2.x; S##b2r_5 = y2.y;                \
  const float2* q1 = (const float2*)((bp) + OFF1);                  \
  float2 z0 = q1[0], z1 = q1[1], z2 = q1[2];                        \
  S##b1_0 = z0.x; S##b1_1 = z0.y; S##b1_2 = z1.x;                   \
  S##b1_3 = z1.y; S##b1_4 = z2.x; S##b1_5 = z2.y;                   \
  S##b2ij = (bp)[oB2ij]; S##b2jk = (bp)[oB2jk];                     \
  S##b3ijk = (bp)[oB3ijk];                                          \
  S##b1k = (bp)[oB1k]; S##b1j = (bp)[oB1j];                         \
}

#define PROD(S) {                                                   \
  const float a1i = sel6(i_, a1_0, a1_1, a1_2, a1_3, a1_4, a1_5);   \
  a4_0 = fmaf(a3, S##b1_0, fmaf(a2, S##b2r_0,                       \
         fmaf(a1i, S##b3r_0, a4_0 + S##b4_0)));                     \
  a4_1 = fmaf(a3, S##b1_1, fmaf(a2, S##b2r_1,                       \
         fmaf(a1i, S##b3r_1, a4_1 + S##b4_1)));                     \
  a4_2 = fmaf(a3, S##b1_2, fmaf(a2, S##b2r_2,                       \
         fmaf(a1i, S##b3r_2, a4_2 + S##b4_2)));                     \
  a4_3 = fmaf(a3, S##b1_3, fmaf(a2, S##b2r_3,                       \
         fmaf(a1i, S##b3r_3, a4_3 + S##b4_3)));                     \
  a4_4 = fmaf(a3, S##b1_4, fmaf(a2, S##b2r_4,                       \
         fmaf(a1i, S##b3r_4, a4_4 + S##b4_4)));                     \
  a4_5 = fmaf(a3, S##b1_5, fmaf(a2, S##b2r_5,                       \
         fmaf(a1i, S##b3r_5, a4_5 + S##b4_5)));                     \
  a3 = fmaf(a2, S##b1k, fmaf(a1i, S##b2jk, a3 + S##b3ijk));         \
  a2 = fmaf(a1i, S##b1j, a2 + S##b2ij);                             \
  a1_0 += S##b1_0; a1_1 += S##b1_1; a1_2 += S##b1_2;                \
  a1_3 += S##b1_3; a1_4 += S##b1_4; a1_5 += S##b1_5;                \
}

__global__ __launch_bounds__(256)
__attribute__((amdgpu_waves_per_eu(1, 1)))
void sig_combine(const float* __restrict__ in,
                 float* __restrict__ out,
                 int n_total, int group,
                 int final_out) {
  const int b = blockIdx.x;
  const int p = threadIdx.x;
  const int start = b * group;
  int end = start + group; if (end > n_total) end = n_total;
  const int tc = (p < 216) ? p : 215;
  const bool act = (p < 216);
  const int k_ = tc % 6;
  const int ij = tc / 6;
  const int j_ = ij % 6;
  const int i_ = ij / 6;

  // loop-invariant element offsets
  const int oB4 = OFF4 + tc * 6;
  const int oB3r = OFF3 + (j_ * 6 + k_) * 6;
  const int oB2r = OFF2 + k_ * 6;
  const int oB2ij = OFF2 + ij;
  const int oB2jk = OFF2 + j_ * 6 + k_;
  const int oB3ijk = OFF3 + tc;
  const int oB1k = OFF1 + k_;
  const int oB1j = OFF1 + j_;

  // ---- init A from state `start` ----
  const float* sp0 = in + (size_t)start * PSTRIDE;
  float a4_0, a4_1, a4_2, a4_3, a4_4, a4_5;
  {
    const float2* q4 = (const float2*)(sp0 + oB4);
    float2 u0 = q4[0], u1 = q4[1], u2 = q4[2];
    a4_0 = u0.x; a4_1 = u0.y; a4_2 = u1.x;
    a4_3 = u1.y; a4_4 = u2.x; a4_5 = u2.y;
  }
  float a3 = sp0[oB3ijk];
  float a2 = sp0[oB2ij];
  float a1_0, a1_1, a1_2, a1_3, a1_4, a1_5;
  {
    const float2* q1 = (const float2*)(sp0 + OFF1);
    float2 z0 = q1[0], z1 = q1[1], z2 = q1[2];
    a1_0 = z0.x; a1_1 = z0.y; a1_2 = z1.x;
    a1_3 = z1.y; a1_4 = z2.x; a1_5 = z2.y;
  }

  DECLSET(A)
  DECLSET(B)
  DECLSET(C)
  DECLSET(D)

#define CLAMP_S(t) (((t) < end) ? (t) : (end - 1))
  int s = start + 1;
  {
    LOADSET(A, in + (size_t)CLAMP_S(s) * PSTRIDE)
    LOADSET(B, in + (size_t)CLAMP_S(s + 1) * PSTRIDE)
    LOADSET(C, in + (size_t)CLAMP_S(s + 2) * PSTRIDE)
    LOADSET(D, in + (size_t)CLAMP_S(s + 3) * PSTRIDE)
  }
  while (s + 3 < end) {
    PROD(A)
    LOADSET(A, in + (size_t)CLAMP_S(s + 4) * PSTRIDE)
    PROD(B)
    LOADSET(B, in + (size_t)CLAMP_S(s + 5) * PSTRIDE)
    PROD(C)
    LOADSET(C, in + (size_t)CLAMP_S(s + 6) * PSTRIDE)
    PROD(D)
    LOADSET(D, in + (size_t)CLAMP_S(s + 7) * PSTRIDE)
    s += 4;
  }
  // tail: at most 3 remaining links, held in A,B,C (D would imply s+3<end)
  if (s < end) { PROD(A) }
  if (s + 1 < end) { PROD(B) }
  if (s + 2 < end) { PROD(C) }
#undef CLAMP_S

  const float a1p = sel6(p, a1_0, a1_1, a1_2, a1_3, a1_4, a1_5);
  if (final_out) {
    float* o = out;   // reference layout: L1 0, L2 6, L3 42, L4 258
    if (act) {
      float2* o2 = (float2*)(o + 258 + tc * 6);
      float2 w;
      w.x = a4_0; w.y = a4_1; o2[0] = w;
      w.x = a4_2; w.y = a4_3; o2[1] = w;
      w.x = a4_4; w.y = a4_5; o2[2] = w;
      o[42 + tc] = a3;
      if (k_ == 0) o[6 + ij] = a2;
    }
    if (p < 6) o[p] = a1p;
  } else {
    float* st = out + (size_t)b * PSTRIDE;
    if (act) {
      float2* o2 = (float2*)(st + oB4);
      float2 w;
      w.x = a4_0; w.y = a4_1; o2[0] = w;
      w.x = a4_2; w.y = a4_3; o2[1] = w;
      w.x = a4_4; w.y = a4_5; o2[2] = w;
      st[oB3ijk] = a3;
      if (k_ == 0) st[oB2ij] = a2;
    }
    if (p < 6) st[OFF1 + p] = a1p;
  }
}

extern "C" void kernel_launch(void* const* d_in, const int* in_sizes, int n_in,
                              void* d_out, int out_size, void* d_ws, size_t ws_size,
                              hipStream_t stream) {
  const float* x = (const float*)d_in[0];
  const int Lrows = in_sizes[0] / 6;
  const int n_inc = Lrows - 1;

  int P = PMAX;
  int chunk_len = (n_inc + P - 1) / P;
  if (chunk_len > VROWS - 3) {             // keep LDS increment staging in bounds
    chunk_len = VROWS - 3;
    P = (n_inc + chunk_len - 1) / chunk_len;
  }

  float* ws0 = (float*)d_ws;                               // P chunk states
  float* ws1 = ws0 + (size_t)PMAX * PSTRIDE;               // tree partials

  sig_chunk<<<P, 64, 0, stream>>>(x, ws0, n_inc, chunk_len);

  float* cur = ws0;
  float* other = ws1;
  int n = P;
  while (n > 1) {
    const int g = (n <= 16) ? n : 16;
    const int nb = (n + g - 1) / g;
    const int fin = (nb == 1);
    sig_combine<<<nb, 256, 0, stream>>>(cur, fin ? (float*)d_out : other, n, g, fin);
    float* t = cur; cur = other; other = t;
    n = nb;
  }
}